// Round 1
// baseline (23124.306 us; speedup 1.0000x reference)
//
#include <hip/hip_runtime.h>
#include <stdint.h>

#define T_STEPS 512
#define B_ALL   512
#define SDIM    64
#define HID     128
#define ADIM    10
#define NCHUNK  16
#define CB      32      // batch rows per chunk
#define PSTEP   16u     // counter increments per chunk-layer-step (8 WGs * 2 waves)
#define LDSS    136     // padded LDS row stride (ushort units): 128 + 8 -> 2-way-free banks

typedef __attribute__((ext_vector_type(4))) float f32x4;
typedef __attribute__((ext_vector_type(8))) short s16x8;
typedef __attribute__((ext_vector_type(4))) unsigned int u32x4;

#define MFMA(a,b,c) __builtin_amdgcn_mfma_f32_16x16x32_bf16(a,b,c,0,0,0)

__device__ __forceinline__ unsigned short bf_rne(float f){
    union{float f; unsigned int u;} v; v.f = f;
    unsigned int r = v.u + 0x7fffu + ((v.u >> 16) & 1u);
    return (unsigned short)(r >> 16);
}
__device__ __forceinline__ float us_to_f(unsigned short h){
    union{unsigned int u; float f;} v; v.u = ((unsigned int)h) << 16; return v.f;
}
__device__ __forceinline__ void split_pair(float f, unsigned short& hi, unsigned short& lo){
    hi = bf_rne(f);
    lo = bf_rne(f - us_to_f(hi));
}
__device__ __forceinline__ void load_split8(const float* p, s16x8& h, s16x8& l){
#pragma unroll
    for (int i = 0; i < 8; i++){
        unsigned short a, b; split_pair(p[i], a, b);
        h[i] = (short)a; l[i] = (short)b;
    }
}
__device__ __forceinline__ float sigm(float x){ return 1.f / (1.f + __expf(-x)); }
__device__ __forceinline__ float tanh_f(float x){ return 1.f - 2.f / (__expf(2.f * x) + 1.f); }

__device__ __forceinline__ void wait_ge(uint32_t* p, uint32_t v){
    while (__hip_atomic_load(p, __ATOMIC_ACQUIRE, __HIP_MEMORY_SCOPE_AGENT) < v)
        __builtin_amdgcn_s_sleep(2);
}

// copy one 32x128 ushort chunk (global, row stride HID) -> LDS (row stride LDSS)
__device__ __forceinline__ void stage_h(const unsigned short* g, unsigned short* d, int tid){
    int row = tid >> 3, col = (tid & 7) * 16;
    const u32x4* s = (const u32x4*)(g + (size_t)row * HID + col);
    u32x4* p = (u32x4*)(d + row * LDSS + col);
    p[0] = s[0]; p[1] = s[1];
}
__device__ __forceinline__ unsigned int pack2(unsigned short a, unsigned short b){
    return (unsigned int)a | ((unsigned int)b << 16);
}
// stage 32x64 f32 x-chunk -> split bf16 hi/lo LDS
__device__ __forceinline__ void stage_x(const float* xg, unsigned short* dh, unsigned short* dl, int tid){
    int row = tid >> 3, col = (tid & 7) * 8;
    const float* s = xg + (size_t)row * SDIM + col;
    unsigned short hs[8], ls[8];
#pragma unroll
    for (int i = 0; i < 8; i++) split_pair(s[i], hs[i], ls[i]);
    u32x4 hv, lv;
#pragma unroll
    for (int i = 0; i < 4; i++){ hv[i] = pack2(hs[2*i], hs[2*i+1]); lv[i] = pack2(ls[2*i], ls[2*i+1]); }
    *(u32x4*)(dh + row * LDSS + col) = hv;
    *(u32x4*)(dl + row * LDSS + col) = lv;
}
__device__ __forceinline__ s16x8 frag(const unsigned short* arr, int row, int k){
    return *(const s16x8*)(arr + row * LDSS + k);
}

__global__ void __launch_bounds__(256, 1)
lstm_fused(const float* __restrict__ x,
           const float* __restrict__ Wih0, const float* __restrict__ Whh0,
           const float* __restrict__ bih0, const float* __restrict__ bhh0,
           const float* __restrict__ Wih1, const float* __restrict__ Whh1,
           const float* __restrict__ bih1, const float* __restrict__ bhh1,
           const float* __restrict__ Wout, const float* __restrict__ bout,
           float* __restrict__ out, unsigned char* __restrict__ ws)
{
    extern __shared__ char smem[];
    unsigned short* A0h = (unsigned short*)smem;          // [32][136] each
    unsigned short* A0l = A0h + CB * LDSS;
    unsigned short* A1h = A0l + CB * LDSS;
    unsigned short* A1l = A1h + CB * LDSS;
    float* part = (float*)(A1l + CB * LDSS);              // 8 slots * 256 f32

    const int tid  = threadIdx.x;
    const int wave = tid >> 6, lane = tid & 63;
    const int lm = lane & 15, lq = lane >> 4;
    const int mt = wave & 1, kh = wave >> 1;

    const int wg = blockIdx.x;
    const int chunk = wg >> 4, sub = wg & 15;
    const int layer = sub >> 3, slice = sub & 7;
    const int b0 = chunk * CB;

    uint32_t* cnt0 = (uint32_t*)(ws + chunk * 64);
    uint32_t* cnt1 = (uint32_t*)(ws + 4096 + chunk * 64);
    unsigned short* h0h = (unsigned short*)(ws + 8192);   // [2][512][128] each
    unsigned short* h0l = h0h + 2 * B_ALL * HID;
    unsigned short* h1h = h0l + 2 * B_ALL * HID;
    unsigned short* h1l = h1h + 2 * B_ALL * HID;

    if (layer == 0){
        // ---- layer 0: gates = x @ Wih0^T + h0 @ Whh0^T (+biases) ----
        s16x8 wh[4][3], wl[4][3];
#pragma unroll
        for (int g = 0; g < 4; g++)
#pragma unroll
            for (int ktl = 0; ktl < 3; ktl++){
                int kt = kh * 3 + ktl;
                int j = g * HID + slice * 16 + lm;
                const float* src = (kt < 2) ? (Wih0 + (size_t)j * SDIM + kt * 32 + lq * 8)
                                            : (Whh0 + (size_t)j * HID + (kt - 2) * 32 + lq * 8);
                load_split8(src, wh[g][ktl], wl[g][ktl]);
            }
        float bias[4];
#pragma unroll
        for (int g = 0; g < 4; g++){
            int j = g * HID + slice * 16 + lm;
            bias[g] = bih0[j] + bhh0[j];
        }
        float cst[4] = {0.f, 0.f, 0.f, 0.f};

        for (int t = 0; t < T_STEPS; t++){
            if (t > 0) wait_ge(cnt0, PSTEP * (uint32_t)t);        // siblings' h0(t-1)
            if (t > 1) wait_ge(cnt1, PSTEP * (uint32_t)(t - 1));  // layer1 done t-2 (slot reuse)
            __syncthreads();                                      // prev-step LDS reads done
            stage_x(x + ((size_t)t * B_ALL + b0) * SDIM, A0h, A0l, tid);
            {
                size_t so = ((size_t)((t & 1) ^ 1) * B_ALL + b0) * HID;   // slot (t-1)&1
                stage_h(h0h + so, A1h, tid);
                stage_h(h0l + so, A1l, tid);
            }
            __syncthreads();

            f32x4 acc[4];
#pragma unroll
            for (int g = 0; g < 4; g++) acc[g] = (f32x4){0.f, 0.f, 0.f, 0.f};
#pragma unroll
            for (int ktl = 0; ktl < 3; ktl++){
                int kt = kh * 3 + ktl;
                const unsigned short* Bh = (kt < 2) ? A0h : A1h;
                const unsigned short* Bl = (kt < 2) ? A0l : A1l;
                int k = (kt < 2) ? kt * 32 : (kt - 2) * 32;
                s16x8 ah = frag(Bh, mt * 16 + lm, k + lq * 8);
                s16x8 al = frag(Bl, mt * 16 + lm, k + lq * 8);
#pragma unroll
                for (int g = 0; g < 4; g++){
                    acc[g] = MFMA(ah, wh[g][ktl], acc[g]);
                    acc[g] = MFMA(ah, wl[g][ktl], acc[g]);
                    acc[g] = MFMA(al, wh[g][ktl], acc[g]);
                }
            }
            if (wave >= 2){
#pragma unroll
                for (int g = 0; g < 4; g++)
                    *(f32x4*)(part + ((wave - 2) * 4 + g) * 256 + lane * 4) = acc[g];
            }
            __syncthreads();
            if (wave < 2){
#pragma unroll
                for (int g = 0; g < 4; g++){
                    f32x4 p = *(f32x4*)(part + (wave * 4 + g) * 256 + lane * 4);
                    acc[g] += p;
                }
                size_t off = ((size_t)(t & 1) * B_ALL + b0 + mt * 16 + lq * 4) * HID + slice * 16 + lm;
#pragma unroll
                for (int r = 0; r < 4; r++){
                    float zi = acc[0][r] + bias[0], zf = acc[1][r] + bias[1];
                    float zg = acc[2][r] + bias[2], zo = acc[3][r] + bias[3];
                    float cn = sigm(zf) * cst[r] + sigm(zi) * tanh_f(zg);
                    float hn = sigm(zo) * tanh_f(cn);
                    cst[r] = cn;
                    unsigned short hh, hl; split_pair(hn, hh, hl);
                    h0h[off + (size_t)r * HID] = hh;
                    h0l[off + (size_t)r * HID] = hl;
                }
                __threadfence();
                if (lane == 0) atomicAdd(cnt0, 1u);
            }
        }
    } else {
        // ---- layer 1: gates = h0(t) @ Wih1^T + h1(t-1) @ Whh1^T; also action(t-1) ----
        s16x8 wh[4][4], wl[4][4];
#pragma unroll
        for (int g = 0; g < 4; g++)
#pragma unroll
            for (int ktl = 0; ktl < 4; ktl++){
                int kt = kh * 4 + ktl;
                int j = g * HID + slice * 16 + lm;
                const float* src = (kt < 4) ? (Wih1 + (size_t)j * HID + kt * 32 + lq * 8)
                                            : (Whh1 + (size_t)j * HID + (kt - 4) * 32 + lq * 8);
                load_split8(src, wh[g][ktl], wl[g][ktl]);
            }
        float bias[4];
#pragma unroll
        for (int g = 0; g < 4; g++){
            int j = g * HID + slice * 16 + lm;
            bias[g] = bih1[j] + bhh1[j];
        }
        float cst[4] = {0.f, 0.f, 0.f, 0.f};

        s16x8 oh[4], ol[4];
        float ob = 0.f;
#pragma unroll
        for (int ktl = 0; ktl < 4; ktl++){
#pragma unroll
            for (int i = 0; i < 8; i++){ oh[ktl][i] = 0; ol[ktl][i] = 0; }
        }
        if (wave >= 2){
            if (lm < ADIM){
#pragma unroll
                for (int ktl = 0; ktl < 4; ktl++)
                    load_split8(Wout + (size_t)lm * HID + ktl * 32 + lq * 8, oh[ktl], ol[ktl]);
                ob = bout[lm];
            }
        }

        for (int t = 0; t < T_STEPS; t++){
            wait_ge(cnt0, PSTEP * (uint32_t)(t + 1));            // h0(t) ready
            if (t > 0) wait_ge(cnt1, PSTEP * (uint32_t)t);       // h1(t-1) ready + slot reuse
            __syncthreads();
            {
                size_t s0 = ((size_t)(t & 1) * B_ALL + b0) * HID;         // h0(t)
                size_t s1 = ((size_t)((t & 1) ^ 1) * B_ALL + b0) * HID;   // h1(t-1)
                stage_h(h0h + s0, A0h, tid);
                stage_h(h0l + s0, A0l, tid);
                stage_h(h1h + s1, A1h, tid);
                stage_h(h1l + s1, A1l, tid);
            }
            __syncthreads();

            f32x4 acc[4];
#pragma unroll
            for (int g = 0; g < 4; g++) acc[g] = (f32x4){0.f, 0.f, 0.f, 0.f};
            s16x8 ah[4], al[4];
            const unsigned short* Bh = kh ? A1h : A0h;
            const unsigned short* Bl = kh ? A1l : A0l;
#pragma unroll
            for (int ktl = 0; ktl < 4; ktl++){
                ah[ktl] = frag(Bh, mt * 16 + lm, ktl * 32 + lq * 8);
                al[ktl] = frag(Bl, mt * 16 + lm, ktl * 32 + lq * 8);
#pragma unroll
                for (int g = 0; g < 4; g++){
                    acc[g] = MFMA(ah[ktl], wh[g][ktl], acc[g]);
                    acc[g] = MFMA(ah[ktl], wl[g][ktl], acc[g]);
                    acc[g] = MFMA(al[ktl], wh[g][ktl], acc[g]);
                }
            }
            if (wave >= 2){
#pragma unroll
                for (int g = 0; g < 4; g++)
                    *(f32x4*)(part + ((wave - 2) * 4 + g) * 256 + lane * 4) = acc[g];
            }
            __syncthreads();
            if (wave < 2){
#pragma unroll
                for (int g = 0; g < 4; g++){
                    f32x4 p = *(f32x4*)(part + (wave * 4 + g) * 256 + lane * 4);
                    acc[g] += p;
                }
                size_t off = ((size_t)(t & 1) * B_ALL + b0 + mt * 16 + lq * 4) * HID + slice * 16 + lm;
#pragma unroll
                for (int r = 0; r < 4; r++){
                    float zi = acc[0][r] + bias[0], zf = acc[1][r] + bias[1];
                    float zg = acc[2][r] + bias[2], zo = acc[3][r] + bias[3];
                    float cn = sigm(zf) * cst[r] + sigm(zi) * tanh_f(zg);
                    float hn = sigm(zo) * tanh_f(cn);
                    cst[r] = cn;
                    unsigned short hh, hl; split_pair(hn, hh, hl);
                    h1h[off + (size_t)r * HID] = hh;
                    h1l[off + (size_t)r * HID] = hl;
                }
                __threadfence();
                if (lane == 0) atomicAdd(cnt1, 1u);
            } else if (t > 0){
                // action(t-1) = tanh(h1(t-1) @ Wout^T + bout): reuse A1 frags already in regs
                f32x4 oacc = (f32x4){0.f, 0.f, 0.f, 0.f};
#pragma unroll
                for (int ktl = 0; ktl < 4; ktl++){
                    oacc = MFMA(ah[ktl], oh[ktl], oacc);
                    oacc = MFMA(ah[ktl], ol[ktl], oacc);
                    oacc = MFMA(al[ktl], oh[ktl], oacc);
                }
                if (lm < ADIM){
#pragma unroll
                    for (int r = 0; r < 4; r++){
                        int b = b0 + mt * 16 + lq * 4 + r;
                        out[((size_t)(t - 1) * B_ALL + b) * ADIM + lm] = tanh_f(oacc[r] + ob);
                    }
                }
            }
        }
        // epilogue: action(511) from h1(511) (slot 1)
        wait_ge(cnt1, PSTEP * (uint32_t)T_STEPS);
        __syncthreads();
        {
            size_t s1 = ((size_t)1 * B_ALL + b0) * HID;
            stage_h(h1h + s1, A1h, tid);
            stage_h(h1l + s1, A1l, tid);
        }
        __syncthreads();
        if (wave >= 2){
            f32x4 oacc = (f32x4){0.f, 0.f, 0.f, 0.f};
#pragma unroll
            for (int ktl = 0; ktl < 4; ktl++){
                s16x8 ah = frag(A1h, mt * 16 + lm, ktl * 32 + lq * 8);
                s16x8 al = frag(A1l, mt * 16 + lm, ktl * 32 + lq * 8);
                oacc = MFMA(ah, oh[ktl], oacc);
                oacc = MFMA(ah, ol[ktl], oacc);
                oacc = MFMA(al, oh[ktl], oacc);
            }
            if (lm < ADIM){
#pragma unroll
                for (int r = 0; r < 4; r++){
                    int b = b0 + mt * 16 + lq * 4 + r;
                    out[((size_t)(T_STEPS - 1) * B_ALL + b) * ADIM + lm] = tanh_f(oacc[r] + ob);
                }
            }
        }
    }
}

extern "C" void kernel_launch(void* const* d_in, const int* in_sizes, int n_in,
                              void* d_out, int out_size, void* d_ws, size_t ws_size,
                              hipStream_t stream)
{
    (void)in_sizes; (void)n_in; (void)out_size; (void)ws_size;
    const float* x    = (const float*)d_in[0];
    const float* Wih0 = (const float*)d_in[1];
    const float* Whh0 = (const float*)d_in[2];
    const float* bih0 = (const float*)d_in[3];
    const float* bhh0 = (const float*)d_in[4];
    const float* Wih1 = (const float*)d_in[5];
    const float* Whh1 = (const float*)d_in[6];
    const float* bih1 = (const float*)d_in[7];
    const float* bhh1 = (const float*)d_in[8];
    const float* Wout = (const float*)d_in[9];
    const float* bout = (const float*)d_in[10];

    // ws: [0,1KB) cnt0 (16 x 64B), [4KB,5KB) cnt1, [8KB, 8KB+1MB) h0/h1 hi/lo double-buffers
    const size_t ws_used = 8192 + 4 * (size_t)2 * B_ALL * HID * sizeof(unsigned short);
    hipMemsetAsync(d_ws, 0, ws_used, stream);

    const size_t lds_bytes = 4 * CB * LDSS * sizeof(unsigned short) + 8 * 256 * sizeof(float); // 43008
    hipLaunchKernelGGL(lstm_fused, dim3(256), dim3(256), lds_bytes, stream,
                       x, Wih0, Whh0, bih0, bhh0, Wih1, Whh1, bih1, bhh1, Wout, bout,
                       (float*)d_out, (unsigned char*)d_ws);
}

// Round 2
// 11732.986 us; speedup vs baseline: 1.9709x; 1.9709x over previous
//
#include <hip/hip_runtime.h>
#include <stdint.h>

#define T_STEPS 512
#define B_ALL   512
#define SDIM    64
#define HID     128
#define ADIM    10
#define CB      32      // batch rows per chunk
#define PSTEP   16u     // signals per chunk-layer-step (8 WGs * 2 waves)
#define NSLOT   4       // h double-buffer depth (anti-deps at t-3)

typedef __attribute__((ext_vector_type(4))) float f32x4;
typedef __attribute__((ext_vector_type(8))) short s16x8;

#define MFMA(a,b,c) __builtin_amdgcn_mfma_f32_16x16x32_bf16(a,b,c,0,0,0)
#define SC_AGENT __HIP_MEMORY_SCOPE_AGENT

__device__ __forceinline__ unsigned short bf_rne(float f){
    union{float f; unsigned int u;} v; v.f = f;
    unsigned int r = v.u + 0x7fffu + ((v.u >> 16) & 1u);
    return (unsigned short)(r >> 16);
}
__device__ __forceinline__ float us_to_f(unsigned short h){
    union{unsigned int u; float f;} v; v.u = ((unsigned int)h) << 16; return v.f;
}
__device__ __forceinline__ void split_pair(float f, unsigned short& hi, unsigned short& lo){
    hi = bf_rne(f);
    lo = bf_rne(f - us_to_f(hi));
}
__device__ __forceinline__ void load_split8(const float* p, s16x8& h, s16x8& l){
#pragma unroll
    for (int i = 0; i < 8; i++){
        unsigned short a, b; split_pair(p[i], a, b);
        h[i] = (short)a; l[i] = (short)b;
    }
}
__device__ __forceinline__ float sigm(float x){ return 1.f / (1.f + __expf(-x)); }
__device__ __forceinline__ float tanh_f(float x){ return 1.f - 2.f / (__expf(2.f * x) + 1.f); }

// ---- cross-WG coherent primitives: per-access sc1, no bulk cache ops in loops ----
__device__ __forceinline__ uint32_t cnt_ld(const uint32_t* p){
    return __hip_atomic_load(p, __ATOMIC_RELAXED, SC_AGENT);
}
__device__ __forceinline__ void wait_ge(uint32_t* p, uint32_t v){
    while (cnt_ld(p) < v) __builtin_amdgcn_s_sleep(1);
    (void)__hip_atomic_load(p, __ATOMIC_ACQUIRE, SC_AGENT);   // one acquire per wait
}
__device__ __forceinline__ void h_store(uint32_t* p, uint32_t v){
    __hip_atomic_store(p, v, __ATOMIC_RELAXED, SC_AGENT);     // write-through, no dirty L2
}
// load 8 packed (hi|lo) cols -> hi-frag + lo-frag. p must be 8B aligned.
__device__ __forceinline__ void load_hfrag(const uint32_t* p, s16x8& ah, s16x8& al){
    unsigned long long w[4];
#pragma unroll
    for (int i = 0; i < 4; i++)
        w[i] = __hip_atomic_load((const unsigned long long*)p + i, __ATOMIC_RELAXED, SC_AGENT);
#pragma unroll
    for (int i = 0; i < 4; i++){
        uint32_t a = (uint32_t)w[i], b = (uint32_t)(w[i] >> 32);
        ah[2*i]   = (short)(a >> 16); al[2*i]   = (short)(a & 0xffffu);
        ah[2*i+1] = (short)(b >> 16); al[2*i+1] = (short)(b & 0xffffu);
    }
}

__global__ void __launch_bounds__(256, 1)
lstm_fused(const float* __restrict__ x,
           const float* __restrict__ Wih0, const float* __restrict__ Whh0,
           const float* __restrict__ bih0, const float* __restrict__ bhh0,
           const float* __restrict__ Wih1, const float* __restrict__ Whh1,
           const float* __restrict__ bih1, const float* __restrict__ bhh1,
           const float* __restrict__ Wout, const float* __restrict__ bout,
           float* __restrict__ out, unsigned char* __restrict__ ws)
{
    extern __shared__ char smem[];
    float* part = (float*)smem;                      // 8 slots * 256 f32 = 8 KB

    const int tid  = threadIdx.x;
    const int wave = tid >> 6, lane = tid & 63;
    const int lm = lane & 15, lq = lane >> 4;
    const int mt = wave & 1, kh = wave >> 1;

    const int wg = blockIdx.x;
    const int chunk = wg >> 4, sub = wg & 15;
    const int layer = sub >> 3, slice = sub & 7;
    const int b0 = chunk * CB;

    uint32_t* cnt0 = (uint32_t*)(ws + chunk * 64);
    uint32_t* cnt1 = (uint32_t*)(ws + 4096 + chunk * 64);
    uint32_t* h0p  = (uint32_t*)(ws + 8192);                 // [NSLOT][512][128] packed hi|lo
    uint32_t* h1p  = h0p + (size_t)NSLOT * B_ALL * HID;

    if (layer == 0){
        // ---- layer 0: gates = x @ Wih0^T + h0(t-1) @ Whh0^T ----
        // K = 64 (x: kt 0,1) + 128 (h0: kt 2..5); kh=0 -> kt{0,1,2}, kh=1 -> kt{3,4,5}
        s16x8 wh[4][3], wl[4][3];
#pragma unroll
        for (int g = 0; g < 4; g++)
#pragma unroll
            for (int ktl = 0; ktl < 3; ktl++){
                int kt = kh * 3 + ktl;
                int j = g * HID + slice * 16 + lm;
                const float* src = (kt < 2) ? (Wih0 + (size_t)j * SDIM + kt * 32 + lq * 8)
                                            : (Whh0 + (size_t)j * HID + (kt - 2) * 32 + lq * 8);
                load_split8(src, wh[g][ktl], wl[g][ktl]);
            }
        float bias[4];
#pragma unroll
        for (int g = 0; g < 4; g++){
            int j = g * HID + slice * 16 + lm;
            bias[g] = bih0[j] + bhh0[j];
        }
        float cst[4] = {0.f, 0.f, 0.f, 0.f};

        for (int t = 0; t < T_STEPS; t++){
            // x(t) is dependency-free: issue loads before any wait
            s16x8 Ah[3], Al[3];
            if (kh == 0){
                const float* xp = x + ((size_t)t * B_ALL + b0 + mt * 16 + lm) * SDIM;
                float v[16];
#pragma unroll
                for (int kt = 0; kt < 2; kt++)
#pragma unroll
                    for (int j = 0; j < 8; j++) v[kt * 8 + j] = xp[kt * 32 + lq * 8 + j];
#pragma unroll
                for (int kt = 0; kt < 2; kt++)
#pragma unroll
                    for (int j = 0; j < 8; j++){
                        unsigned short hh, ll; split_pair(v[kt * 8 + j], hh, ll);
                        Ah[kt][j] = (short)hh; Al[kt][j] = (short)ll;
                    }
            }
            if (t > 0) wait_ge(cnt0, PSTEP * (uint32_t)t);           // h0(t-1) ready
            if (t > 3) wait_ge(cnt1, PSTEP * (uint32_t)(t - 3));     // slot t&3 reusable

            const uint32_t* hr = h0p + ((size_t)((t - 1) & 3) * B_ALL + b0 + mt * 16 + lm) * HID;
            if (kh == 0){
                load_hfrag(hr + 0 + lq * 8, Ah[2], Al[2]);           // h0 cols 0..31
            } else {
#pragma unroll
                for (int i = 0; i < 3; i++)
                    load_hfrag(hr + 32 + i * 32 + lq * 8, Ah[i], Al[i]);   // h0 cols 32..127
            }

            f32x4 acc[4];
#pragma unroll
            for (int g = 0; g < 4; g++) acc[g] = (f32x4){0.f, 0.f, 0.f, 0.f};
#pragma unroll
            for (int ktl = 0; ktl < 3; ktl++)
#pragma unroll
                for (int g = 0; g < 4; g++){
                    acc[g] = MFMA(Ah[ktl], wh[g][ktl], acc[g]);
                    acc[g] = MFMA(Ah[ktl], wl[g][ktl], acc[g]);
                    acc[g] = MFMA(Al[ktl], wh[g][ktl], acc[g]);
                }

            if (wave >= 2){
#pragma unroll
                for (int g = 0; g < 4; g++)
                    *(f32x4*)(part + ((wave - 2) * 4 + g) * 256 + lane * 4) = acc[g];
            }
            __syncthreads();
            if (wave < 2){
#pragma unroll
                for (int g = 0; g < 4; g++)
                    acc[g] += *(f32x4*)(part + (wave * 4 + g) * 256 + lane * 4);
                uint32_t* wrow = h0p + ((size_t)(t & 3) * B_ALL + b0 + mt * 16 + lq * 4) * HID
                               + slice * 16 + lm;
#pragma unroll
                for (int r = 0; r < 4; r++){
                    float zi = acc[0][r] + bias[0], zf = acc[1][r] + bias[1];
                    float zg = acc[2][r] + bias[2], zo = acc[3][r] + bias[3];
                    float cn = sigm(zf) * cst[r] + sigm(zi) * tanh_f(zg);
                    float hn = sigm(zo) * tanh_f(cn);
                    cst[r] = cn;
                    unsigned short hh, ll; split_pair(hn, hh, ll);
                    h_store(wrow + (size_t)r * HID, ((uint32_t)hh << 16) | (uint32_t)ll);
                }
                if (lane == 0)
                    __hip_atomic_fetch_add(cnt0, 1u, __ATOMIC_RELEASE, SC_AGENT);
            }
        }
    } else {
        // ---- layer 1: gates = h0(t) @ Wih1^T + h1(t-1) @ Whh1^T; + action(t-1) ----
        // K = 128 (h0: kt 0..3) + 128 (h1: kt 4..7); kh=0 -> h0 half, kh=1 -> h1 half
        s16x8 wh[4][4], wl[4][4];
#pragma unroll
        for (int g = 0; g < 4; g++)
#pragma unroll
            for (int ktl = 0; ktl < 4; ktl++){
                int kt = kh * 4 + ktl;
                int j = g * HID + slice * 16 + lm;
                const float* src = (kt < 4) ? (Wih1 + (size_t)j * HID + kt * 32 + lq * 8)
                                            : (Whh1 + (size_t)j * HID + (kt - 4) * 32 + lq * 8);
                load_split8(src, wh[g][ktl], wl[g][ktl]);
            }
        float bias[4];
#pragma unroll
        for (int g = 0; g < 4; g++){
            int j = g * HID + slice * 16 + lm;
            bias[g] = bih1[j] + bhh1[j];
        }
        float cst[4] = {0.f, 0.f, 0.f, 0.f};

        s16x8 oh[4], ol[4];
        float ob = 0.f;
#pragma unroll
        for (int ktl = 0; ktl < 4; ktl++)
#pragma unroll
            for (int i = 0; i < 8; i++){ oh[ktl][i] = 0; ol[ktl][i] = 0; }
        if (kh == 1 && lm < ADIM){
#pragma unroll
            for (int ktl = 0; ktl < 4; ktl++)
                load_split8(Wout + (size_t)lm * HID + ktl * 32 + lq * 8, oh[ktl], ol[ktl]);
            ob = bout[lm];
        }

        for (int t = 0; t < T_STEPS; t++){
            if (kh == 0) wait_ge(cnt0, PSTEP * (uint32_t)(t + 1));      // h0(t) ready
            else if (t > 0) wait_ge(cnt1, PSTEP * (uint32_t)t);         // h1(t-1) ready

            s16x8 Ah[4], Al[4];
            {
                const uint32_t* hr = (kh == 0)
                    ? (h0p + ((size_t)(t & 3) * B_ALL + b0 + mt * 16 + lm) * HID)
                    : (h1p + ((size_t)((t - 1) & 3) * B_ALL + b0 + mt * 16 + lm) * HID);
#pragma unroll
                for (int i = 0; i < 4; i++)
                    load_hfrag(hr + i * 32 + lq * 8, Ah[i], Al[i]);
            }

            f32x4 acc[4];
#pragma unroll
            for (int g = 0; g < 4; g++) acc[g] = (f32x4){0.f, 0.f, 0.f, 0.f};
#pragma unroll
            for (int ktl = 0; ktl < 4; ktl++)
#pragma unroll
                for (int g = 0; g < 4; g++){
                    acc[g] = MFMA(Ah[ktl], wh[g][ktl], acc[g]);
                    acc[g] = MFMA(Ah[ktl], wl[g][ktl], acc[g]);
                    acc[g] = MFMA(Al[ktl], wh[g][ktl], acc[g]);
                }

            if (wave >= 2){
#pragma unroll
                for (int g = 0; g < 4; g++)
                    *(f32x4*)(part + ((wave - 2) * 4 + g) * 256 + lane * 4) = acc[g];
            }
            __syncthreads();
            if (wave < 2){
#pragma unroll
                for (int g = 0; g < 4; g++)
                    acc[g] += *(f32x4*)(part + (wave * 4 + g) * 256 + lane * 4);
                uint32_t* wrow = h1p + ((size_t)(t & 3) * B_ALL + b0 + mt * 16 + lq * 4) * HID
                               + slice * 16 + lm;
#pragma unroll
                for (int r = 0; r < 4; r++){
                    float zi = acc[0][r] + bias[0], zf = acc[1][r] + bias[1];
                    float zg = acc[2][r] + bias[2], zo = acc[3][r] + bias[3];
                    float cn = sigm(zf) * cst[r] + sigm(zi) * tanh_f(zg);
                    float hn = sigm(zo) * tanh_f(cn);
                    cst[r] = cn;
                    unsigned short hh, ll; split_pair(hn, hh, ll);
                    h_store(wrow + (size_t)r * HID, ((uint32_t)hh << 16) | (uint32_t)ll);
                }
                if (lane == 0)
                    __hip_atomic_fetch_add(cnt1, 1u, __ATOMIC_RELEASE, SC_AGENT);
            } else if (t > 0){
                // action(t-1) = tanh(h1(t-1) @ Wout^T + bout): reuse h1 frags in regs
                f32x4 oacc = (f32x4){0.f, 0.f, 0.f, 0.f};
#pragma unroll
                for (int ktl = 0; ktl < 4; ktl++){
                    oacc = MFMA(Ah[ktl], oh[ktl], oacc);
                    oacc = MFMA(Ah[ktl], ol[ktl], oacc);
                    oacc = MFMA(Al[ktl], oh[ktl], oacc);
                }
                if (lm < ADIM){
#pragma unroll
                    for (int r = 0; r < 4; r++){
                        int b = b0 + mt * 16 + lq * 4 + r;
                        out[((size_t)(t - 1) * B_ALL + b) * ADIM + lm] = tanh_f(oacc[r] + ob);
                    }
                }
            }
        }
        // epilogue: action(511) from h1(511) (slot 511&3 = 3)
        if (kh == 1){
            wait_ge(cnt1, PSTEP * (uint32_t)T_STEPS);
            const uint32_t* hr = h1p + ((size_t)3 * B_ALL + b0 + mt * 16 + lm) * HID;
            s16x8 Ah, Al;
            f32x4 oacc = (f32x4){0.f, 0.f, 0.f, 0.f};
#pragma unroll
            for (int ktl = 0; ktl < 4; ktl++){
                load_hfrag(hr + ktl * 32 + lq * 8, Ah, Al);
                oacc = MFMA(Ah, oh[ktl], oacc);
                oacc = MFMA(Ah, ol[ktl], oacc);
                oacc = MFMA(Al, oh[ktl], oacc);
            }
            if (lm < ADIM){
#pragma unroll
                for (int r = 0; r < 4; r++){
                    int b = b0 + mt * 16 + lq * 4 + r;
                    out[((size_t)(T_STEPS - 1) * B_ALL + b) * ADIM + lm] = tanh_f(oacc[r] + ob);
                }
            }
        }
    }
}

extern "C" void kernel_launch(void* const* d_in, const int* in_sizes, int n_in,
                              void* d_out, int out_size, void* d_ws, size_t ws_size,
                              hipStream_t stream)
{
    (void)in_sizes; (void)n_in; (void)out_size; (void)ws_size;
    const float* x    = (const float*)d_in[0];
    const float* Wih0 = (const float*)d_in[1];
    const float* Whh0 = (const float*)d_in[2];
    const float* bih0 = (const float*)d_in[3];
    const float* bhh0 = (const float*)d_in[4];
    const float* Wih1 = (const float*)d_in[5];
    const float* Whh1 = (const float*)d_in[6];
    const float* bih1 = (const float*)d_in[7];
    const float* bhh1 = (const float*)d_in[8];
    const float* Wout = (const float*)d_in[9];
    const float* bout = (const float*)d_in[10];

    // ws: [0,1KB) cnt0 (16 x 64B), [4KB,5KB) cnt1,
    //     [8KB, ...) h0/h1 packed(hi|lo) u32 buffers, NSLOT slots each
    const size_t ws_used = 8192 + 2 * (size_t)NSLOT * B_ALL * HID * sizeof(uint32_t); // ~2.1 MB
    hipMemsetAsync(d_ws, 0, ws_used, stream);

    const size_t lds_bytes = 8 * 256 * sizeof(float);   // 8 KB partial-sum buffer
    hipLaunchKernelGGL(lstm_fused, dim3(256), dim3(256), lds_bytes, stream,
                       x, Wih0, Whh0, bih0, bhh0, Wih1, Whh1, bih1, bhh1, Wout, bout,
                       (float*)d_out, (unsigned char*)d_ws);
}

// Round 3
// 2966.260 us; speedup vs baseline: 7.7958x; 3.9555x over previous
//
#include <hip/hip_runtime.h>
#include <stdint.h>

#define T_STEPS 512
#define B_ALL   512
#define SDIM    64
#define HID     128
#define ADIM    10
#define CB      32      // batch rows per chunk
#define PSTEP   16u     // signals per chunk-layer-step (8 WGs * 2 waves)
#define NSLOT   4       // h buffer depth (anti-deps at t-3)

typedef __attribute__((ext_vector_type(4))) float f32x4;
typedef __attribute__((ext_vector_type(8))) short s16x8;

#define MFMA(a,b,c) __builtin_amdgcn_mfma_f32_16x16x32_bf16(a,b,c,0,0,0)
#define SC_AGENT __HIP_MEMORY_SCOPE_AGENT

__device__ __forceinline__ unsigned short bf_rne(float f){
    union{float f; unsigned int u;} v; v.f = f;
    unsigned int r = v.u + 0x7fffu + ((v.u >> 16) & 1u);
    return (unsigned short)(r >> 16);
}
__device__ __forceinline__ float us_to_f(unsigned short h){
    union{unsigned int u; float f;} v; v.u = ((unsigned int)h) << 16; return v.f;
}
__device__ __forceinline__ void split_pair(float f, unsigned short& hi, unsigned short& lo){
    hi = bf_rne(f);
    lo = bf_rne(f - us_to_f(hi));
}
__device__ __forceinline__ void load_split8(const float* p, s16x8& h, s16x8& l){
#pragma unroll
    for (int i = 0; i < 8; i++){
        unsigned short a, b; split_pair(p[i], a, b);
        h[i] = (short)a; l[i] = (short)b;
    }
}
__device__ __forceinline__ float sigm(float x){ return 1.f / (1.f + __expf(-x)); }
__device__ __forceinline__ float tanh_f(float x){ return 1.f - 2.f / (__expf(2.f * x) + 1.f); }

// ---- cross-WG relaxed-only protocol: all shared data is sc1 (device coherence
// point) atomics, so NO acquire buffer_inv / release buffer_wbl2 is needed.
// Producer ordering = per-wave vmcnt(0) drain before the counter bump.
__device__ __forceinline__ uint32_t cnt_ld(const uint32_t* p){
    return __hip_atomic_load(p, __ATOMIC_RELAXED, SC_AGENT);
}
// monotonic counters: shadow-cache last seen value, skip load when satisfied
__device__ __forceinline__ void wait_ge(uint32_t* p, uint32_t v, uint32_t& seen){
    if (seen >= v) return;
    uint32_t c;
    while ((c = cnt_ld(p)) < v) __builtin_amdgcn_s_sleep(1);
    seen = c;
    __asm__ volatile("" ::: "memory");
}
__device__ __forceinline__ void signal_add(uint32_t* p){
    __asm__ volatile("" ::: "memory");
    __builtin_amdgcn_s_waitcnt(0x0f70);   // vmcnt(0): h stores acked at coherence point
    __hip_atomic_fetch_add(p, 1u, __ATOMIC_RELAXED, SC_AGENT);
}
__device__ __forceinline__ void h_store(uint32_t* p, uint32_t v){
    __hip_atomic_store(p, v, __ATOMIC_RELAXED, SC_AGENT);     // write-through sc1
}
// load 8 packed (hi|lo) cols -> hi-frag + lo-frag. p must be 8B aligned.
__device__ __forceinline__ void load_hfrag(const uint32_t* p, s16x8& ah, s16x8& al){
    unsigned long long w[4];
#pragma unroll
    for (int i = 0; i < 4; i++)
        w[i] = __hip_atomic_load((const unsigned long long*)p + i, __ATOMIC_RELAXED, SC_AGENT);
#pragma unroll
    for (int i = 0; i < 4; i++){
        uint32_t a = (uint32_t)w[i], b = (uint32_t)(w[i] >> 32);
        ah[2*i]   = (short)(a >> 16); al[2*i]   = (short)(a & 0xffffu);
        ah[2*i+1] = (short)(b >> 16); al[2*i+1] = (short)(b & 0xffffu);
    }
}

__global__ void __launch_bounds__(256, 1)
lstm_fused(const float* __restrict__ x,
           const float* __restrict__ Wih0, const float* __restrict__ Whh0,
           const float* __restrict__ bih0, const float* __restrict__ bhh0,
           const float* __restrict__ Wih1, const float* __restrict__ Whh1,
           const float* __restrict__ bih1, const float* __restrict__ bhh1,
           const float* __restrict__ Wout, const float* __restrict__ bout,
           float* __restrict__ out, unsigned char* __restrict__ ws)
{
    extern __shared__ char smem[];
    float* part = (float*)smem;                      // 8 slots * 256 f32 = 8 KB

    const int tid  = threadIdx.x;
    const int wave = tid >> 6, lane = tid & 63;
    const int lm = lane & 15, lq = lane >> 4;
    const int mt = wave & 1, kh = wave >> 1;

    const int wg = blockIdx.x;
    const int chunk = wg >> 4, sub = wg & 15;
    const int layer = sub >> 3, slice = sub & 7;
    const int b0 = chunk * CB;

    uint32_t* cnt0 = (uint32_t*)(ws + chunk * 64);
    uint32_t* cnt1 = (uint32_t*)(ws + 4096 + chunk * 64);
    uint32_t* h0p  = (uint32_t*)(ws + 8192);                 // [NSLOT][512][128] packed hi|lo
    uint32_t* h1p  = h0p + (size_t)NSLOT * B_ALL * HID;

    uint32_t seen0 = 0, seen1 = 0;                           // counter shadows

    if (layer == 0){
        // ---- layer 0: gates = x @ Wih0^T + h0(t-1) @ Whh0^T ----
        // K = 64 (x: kt 0,1) + 128 (h0: kt 2..5); kh=0 -> kt{0,1,2}, kh=1 -> kt{3,4,5}
        s16x8 wh[4][3], wl[4][3];
#pragma unroll
        for (int g = 0; g < 4; g++)
#pragma unroll
            for (int ktl = 0; ktl < 3; ktl++){
                int kt = kh * 3 + ktl;
                int j = g * HID + slice * 16 + lm;
                const float* src = (kt < 2) ? (Wih0 + (size_t)j * SDIM + kt * 32 + lq * 8)
                                            : (Whh0 + (size_t)j * HID + (kt - 2) * 32 + lq * 8);
                load_split8(src, wh[g][ktl], wl[g][ktl]);
            }
        float bias[4];
#pragma unroll
        for (int g = 0; g < 4; g++){
            int j = g * HID + slice * 16 + lm;
            bias[g] = bih0[j] + bhh0[j];
        }
        float cst[4] = {0.f, 0.f, 0.f, 0.f};

        for (int t = 0; t < T_STEPS; t++){
            // x(t) is dependency-free: issue loads before any wait
            s16x8 Ah[3], Al[3];
            if (kh == 0){
                const float* xp = x + ((size_t)t * B_ALL + b0 + mt * 16 + lm) * SDIM;
                float v[16];
#pragma unroll
                for (int kt = 0; kt < 2; kt++)
#pragma unroll
                    for (int j = 0; j < 8; j++) v[kt * 8 + j] = xp[kt * 32 + lq * 8 + j];
#pragma unroll
                for (int kt = 0; kt < 2; kt++)
#pragma unroll
                    for (int j = 0; j < 8; j++){
                        unsigned short hh, ll; split_pair(v[kt * 8 + j], hh, ll);
                        Ah[kt][j] = (short)hh; Al[kt][j] = (short)ll;
                    }
            }
            if (t > 0) wait_ge(cnt0, PSTEP * (uint32_t)t, seen0);        // h0(t-1) ready
            if (t > 3) wait_ge(cnt1, PSTEP * (uint32_t)(t - 3), seen1);  // slot t&3 reusable

            const uint32_t* hr = h0p + ((size_t)((t - 1) & 3) * B_ALL + b0 + mt * 16 + lm) * HID;
            if (kh == 0){
                load_hfrag(hr + 0 + lq * 8, Ah[2], Al[2]);           // h0 cols 0..31
            } else {
#pragma unroll
                for (int i = 0; i < 3; i++)
                    load_hfrag(hr + 32 + i * 32 + lq * 8, Ah[i], Al[i]);   // h0 cols 32..127
            }

            f32x4 acc[4];
#pragma unroll
            for (int g = 0; g < 4; g++) acc[g] = (f32x4){0.f, 0.f, 0.f, 0.f};
#pragma unroll
            for (int ktl = 0; ktl < 3; ktl++)
#pragma unroll
                for (int g = 0; g < 4; g++){
                    acc[g] = MFMA(Ah[ktl], wh[g][ktl], acc[g]);
                    acc[g] = MFMA(Ah[ktl], wl[g][ktl], acc[g]);
                    acc[g] = MFMA(Al[ktl], wh[g][ktl], acc[g]);
                }

            if (wave >= 2){
#pragma unroll
                for (int g = 0; g < 4; g++)
                    *(f32x4*)(part + ((wave - 2) * 4 + g) * 256 + lane * 4) = acc[g];
            }
            __syncthreads();
            if (wave < 2){
#pragma unroll
                for (int g = 0; g < 4; g++)
                    acc[g] += *(f32x4*)(part + (wave * 4 + g) * 256 + lane * 4);
                uint32_t* wrow = h0p + ((size_t)(t & 3) * B_ALL + b0 + mt * 16 + lq * 4) * HID
                               + slice * 16 + lm;
#pragma unroll
                for (int r = 0; r < 4; r++){
                    float zi = acc[0][r] + bias[0], zf = acc[1][r] + bias[1];
                    float zg = acc[2][r] + bias[2], zo = acc[3][r] + bias[3];
                    float cn = sigm(zf) * cst[r] + sigm(zi) * tanh_f(zg);
                    float hn = sigm(zo) * tanh_f(cn);
                    cst[r] = cn;
                    unsigned short hh, ll; split_pair(hn, hh, ll);
                    h_store(wrow + (size_t)r * HID, ((uint32_t)hh << 16) | (uint32_t)ll);
                }
                if (lane == 0) signal_add(cnt0);
            }
        }
    } else {
        // ---- layer 1: gates = h0(t) @ Wih1^T + h1(t-1) @ Whh1^T; + action(t-1) ----
        // K = 128 (h0: kt 0..3) + 128 (h1: kt 4..7); kh=0 -> h0 half, kh=1 -> h1 half
        s16x8 wh[4][4], wl[4][4];
#pragma unroll
        for (int g = 0; g < 4; g++)
#pragma unroll
            for (int ktl = 0; ktl < 4; ktl++){
                int kt = kh * 4 + ktl;
                int j = g * HID + slice * 16 + lm;
                const float* src = (kt < 4) ? (Wih1 + (size_t)j * HID + kt * 32 + lq * 8)
                                            : (Whh1 + (size_t)j * HID + (kt - 4) * 32 + lq * 8);
                load_split8(src, wh[g][ktl], wl[g][ktl]);
            }
        float bias[4];
#pragma unroll
        for (int g = 0; g < 4; g++){
            int j = g * HID + slice * 16 + lm;
            bias[g] = bih1[j] + bhh1[j];
        }
        float cst[4] = {0.f, 0.f, 0.f, 0.f};

        s16x8 oh[4], ol[4];
        float ob = 0.f;
#pragma unroll
        for (int ktl = 0; ktl < 4; ktl++)
#pragma unroll
            for (int i = 0; i < 8; i++){ oh[ktl][i] = 0; ol[ktl][i] = 0; }
        if (kh == 1 && lm < ADIM){
#pragma unroll
            for (int ktl = 0; ktl < 4; ktl++)
                load_split8(Wout + (size_t)lm * HID + ktl * 32 + lq * 8, oh[ktl], ol[ktl]);
            ob = bout[lm];
        }

        for (int t = 0; t < T_STEPS; t++){
            if (kh == 0) wait_ge(cnt0, PSTEP * (uint32_t)(t + 1), seen0);   // h0(t) ready
            else if (t > 0) wait_ge(cnt1, PSTEP * (uint32_t)t, seen1);      // h1(t-1) ready

            s16x8 Ah[4], Al[4];
            {
                const uint32_t* hr = (kh == 0)
                    ? (h0p + ((size_t)(t & 3) * B_ALL + b0 + mt * 16 + lm) * HID)
                    : (h1p + ((size_t)((t - 1) & 3) * B_ALL + b0 + mt * 16 + lm) * HID);
#pragma unroll
                for (int i = 0; i < 4; i++)
                    load_hfrag(hr + i * 32 + lq * 8, Ah[i], Al[i]);
            }

            f32x4 acc[4];
#pragma unroll
            for (int g = 0; g < 4; g++) acc[g] = (f32x4){0.f, 0.f, 0.f, 0.f};
#pragma unroll
            for (int ktl = 0; ktl < 4; ktl++)
#pragma unroll
                for (int g = 0; g < 4; g++){
                    acc[g] = MFMA(Ah[ktl], wh[g][ktl], acc[g]);
                    acc[g] = MFMA(Ah[ktl], wl[g][ktl], acc[g]);
                    acc[g] = MFMA(Al[ktl], wh[g][ktl], acc[g]);
                }

            if (wave >= 2){
#pragma unroll
                for (int g = 0; g < 4; g++)
                    *(f32x4*)(part + ((wave - 2) * 4 + g) * 256 + lane * 4) = acc[g];
            }
            __syncthreads();
            if (wave < 2){
#pragma unroll
                for (int g = 0; g < 4; g++)
                    acc[g] += *(f32x4*)(part + (wave * 4 + g) * 256 + lane * 4);
                uint32_t* wrow = h1p + ((size_t)(t & 3) * B_ALL + b0 + mt * 16 + lq * 4) * HID
                               + slice * 16 + lm;
#pragma unroll
                for (int r = 0; r < 4; r++){
                    float zi = acc[0][r] + bias[0], zf = acc[1][r] + bias[1];
                    float zg = acc[2][r] + bias[2], zo = acc[3][r] + bias[3];
                    float cn = sigm(zf) * cst[r] + sigm(zi) * tanh_f(zg);
                    float hn = sigm(zo) * tanh_f(cn);
                    cst[r] = cn;
                    unsigned short hh, ll; split_pair(hn, hh, ll);
                    h_store(wrow + (size_t)r * HID, ((uint32_t)hh << 16) | (uint32_t)ll);
                }
                if (lane == 0) signal_add(cnt1);
            } else if (t > 0){
                // action(t-1) = tanh(h1(t-1) @ Wout^T + bout): reuse h1 frags in regs
                f32x4 oacc = (f32x4){0.f, 0.f, 0.f, 0.f};
#pragma unroll
                for (int ktl = 0; ktl < 4; ktl++){
                    oacc = MFMA(Ah[ktl], oh[ktl], oacc);
                    oacc = MFMA(Ah[ktl], ol[ktl], oacc);
                    oacc = MFMA(Al[ktl], oh[ktl], oacc);
                }
                if (lm < ADIM){
#pragma unroll
                    for (int r = 0; r < 4; r++){
                        int b = b0 + mt * 16 + lq * 4 + r;
                        out[((size_t)(t - 1) * B_ALL + b) * ADIM + lm] = tanh_f(oacc[r] + ob);
                    }
                }
            }
        }
        // epilogue: action(511) from h1(511) (slot 511&3 = 3)
        if (kh == 1){
            wait_ge(cnt1, PSTEP * (uint32_t)T_STEPS, seen1);
            const uint32_t* hr = h1p + ((size_t)3 * B_ALL + b0 + mt * 16 + lm) * HID;
            s16x8 Ah, Al;
            f32x4 oacc = (f32x4){0.f, 0.f, 0.f, 0.f};
#pragma unroll
            for (int ktl = 0; ktl < 4; ktl++){
                load_hfrag(hr + ktl * 32 + lq * 8, Ah, Al);
                oacc = MFMA(Ah, oh[ktl], oacc);
                oacc = MFMA(Ah, ol[ktl], oacc);
                oacc = MFMA(Al, oh[ktl], oacc);
            }
            if (lm < ADIM){
#pragma unroll
                for (int r = 0; r < 4; r++){
                    int b = b0 + mt * 16 + lq * 4 + r;
                    out[((size_t)(T_STEPS - 1) * B_ALL + b) * ADIM + lm] = tanh_f(oacc[r] + ob);
                }
            }
        }
    }
}

extern "C" void kernel_launch(void* const* d_in, const int* in_sizes, int n_in,
                              void* d_out, int out_size, void* d_ws, size_t ws_size,
                              hipStream_t stream)
{
    (void)in_sizes; (void)n_in; (void)out_size; (void)ws_size;
    const float* x    = (const float*)d_in[0];
    const float* Wih0 = (const float*)d_in[1];
    const float* Whh0 = (const float*)d_in[2];
    const float* bih0 = (const float*)d_in[3];
    const float* bhh0 = (const float*)d_in[4];
    const float* Wih1 = (const float*)d_in[5];
    const float* Whh1 = (const float*)d_in[6];
    const float* bih1 = (const float*)d_in[7];
    const float* bhh1 = (const float*)d_in[8];
    const float* Wout = (const float*)d_in[9];
    const float* bout = (const float*)d_in[10];

    // ws: [0,1KB) cnt0 (16 x 64B), [4KB,5KB) cnt1,
    //     [8KB, ...) h0/h1 packed(hi|lo) u32 buffers, NSLOT slots each
    const size_t ws_used = 8192 + 2 * (size_t)NSLOT * B_ALL * HID * sizeof(uint32_t); // ~2.1 MB
    hipMemsetAsync(d_ws, 0, ws_used, stream);

    const size_t lds_bytes = 8 * 256 * sizeof(float);   // 8 KB partial-sum buffer
    hipLaunchKernelGGL(lstm_fused, dim3(256), dim3(256), lds_bytes, stream,
                       x, Wih0, Whh0, bih0, bhh0, Wih1, Whh1, bih1, bhh1, Wout, bout,
                       (float*)d_out, (unsigned char*)d_ws);
}